// Round 5
// baseline (106.282 us; speedup 1.0000x reference)
//
#include <hip/hip_runtime.h>

// ReactionTerm — gather formulation, SORT-BALANCED ELL-transposed layout.
//
// Build:
//   memset: counts/cursor/ELL zeroed.
//   count_kernel: histogram reactions by product.
//   sort_kernel (1 block): counting-sort products by descending count ->
//     perm[j]=p, iperm[p]=j, cnt_sorted[j].
//   fill_kernel: slot=atomicAdd(cursor[p]); ell[slot][iperm[p]] = record
//     record = int2{ ia | (ib<<16), bitcast(k) }; 1st-order ib=NS sentinel.
//   Zero pad slots decode to k=0 -> contribute exactly 0.
//
// reaction_main_kernel: block = G=4 batch rows x 1024 products, 512 threads.
// Thread t owns sorted columns {2t, 2t+1} (adjacent in sorted order ->
// c0~=c1 and within-wave counts nearly equal -> ~4% pad waste vs ~90% for
// natural order). One coalesced int4 per slot covers both columns' records.
// y_s[s] = float4{rows} staged with conflict-free b128 writes; accumulators
// staged to a_s[product] (LDS) then written back coalesced.

constexpr int BATCH = 4096;
constexpr int NS    = 1024;
constexpr int NR1   = 2048;
constexpr int NR2   = 8192;
constexpr int NRT   = NR1 + NR2;   // 10240
constexpr int G     = 4;
constexpr int MAIN_THREADS = 512;
constexpr int MAX_SLOTS = 64;      // Poisson(lambda~10): P(count>=64) ~ 1e-30

// d_ws layout (bytes) — no overlaps:
//   counts    : int[1024]      @ 0        (4 KiB)
//   cursor    : int[1024]      @ 4096     (4 KiB)
//   ell       : int2[64*1024]  @ 8192     (512 KiB, ends 532480)
//   perm      : int[1024]      @ 532480
//   iperm     : int[1024]      @ 536576
//   cnt_sorted: int[1024]      @ 540672
constexpr size_t WS_COUNTS = 0;
constexpr size_t WS_CURSOR = 4096;
constexpr size_t WS_ELL    = 8192;
constexpr size_t WS_PERM   = 532480;
constexpr size_t WS_IPERM  = 536576;
constexpr size_t WS_CNTS   = 540672;
constexpr size_t WS_ZERO_BYTES = WS_ELL + (size_t)MAX_SLOTS * NS * sizeof(int2);

__global__ __launch_bounds__(256) void count_kernel(
    const int* __restrict__ i1p, const int* __restrict__ i2p,
    int* __restrict__ counts)
{
    const int i = blockIdx.x * blockDim.x + threadIdx.x;
    if (i < NR1)       atomicAdd(&counts[i1p[i]], 1);
    else if (i < NRT)  atomicAdd(&counts[i2p[i - NR1]], 1);
}

__global__ __launch_bounds__(1024) void sort_kernel(
    const int* __restrict__ counts,
    int* __restrict__ perm, int* __restrict__ iperm, int* __restrict__ cnt_sorted)
{
    __shared__ int bins[MAX_SLOTS];
    __shared__ int start[MAX_SLOTS];
    const int tid = threadIdx.x;                 // one product per thread
    if (tid < MAX_SLOTS) bins[tid] = 0;
    __syncthreads();
    const int c = min(counts[tid], MAX_SLOTS - 1);
    atomicAdd(&bins[c], 1);
    __syncthreads();
    if (tid == 0) {                              // descending-count start offsets
        int acc = 0;
        for (int v = MAX_SLOTS - 1; v >= 0; --v) { start[v] = acc; acc += bins[v]; }
    }
    __syncthreads();
    const int j = atomicAdd(&start[c], 1);
    perm[j] = tid;
    iperm[tid] = j;
    cnt_sorted[j] = c;
}

__global__ __launch_bounds__(256) void fill_kernel(
    const float* __restrict__ k1,  const float* __restrict__ k2,
    const int*   __restrict__ i1r, const int*   __restrict__ i1p,
    const int*   __restrict__ i2r, const int*   __restrict__ i2p,
    const int*   __restrict__ iperm,
    int*         __restrict__ cursor,   // [NS], zeroed
    int2*        __restrict__ ell)      // [MAX_SLOTS][NS] sorted-column order
{
    const int i = blockIdx.x * blockDim.x + threadIdx.x;
    if (i < NR1) {
        const int p = i1p[i];
        const int slot = atomicAdd(&cursor[p], 1);
        if (slot < MAX_SLOTS)
            ell[slot * NS + iperm[p]] =
                make_int2(i1r[i] | (NS << 16), __float_as_int(k1[i]));
    } else if (i < NRT) {
        const int r = i - NR1;
        const int p = i2p[r];
        const int slot = atomicAdd(&cursor[p], 1);
        if (slot < MAX_SLOTS)
            ell[slot * NS + iperm[p]] =
                make_int2(i2r[2 * r] | (i2r[2 * r + 1] << 16), __float_as_int(k2[r]));
    }
}

__global__ __launch_bounds__(MAIN_THREADS) void reaction_main_kernel(
    const float* __restrict__ t_in,        // [B]
    const float* __restrict__ y_in,        // [B, NS]
    const int*   __restrict__ cnt_sorted,  // [NS]
    const int*   __restrict__ perm,        // [NS]
    const int4*  __restrict__ ell4,        // [MAX_SLOTS][NS/2] record-pairs
    float*       __restrict__ y_out)       // [B, NS]
{
    __shared__ float4 y_s[NS + 1];   // y_s[s] = {y[b0+g][s]}; [NS] = 1.0 sentinel
    __shared__ float4 a_s[NS];       // a_s[p] = {acc for rows g}

    const int tid = threadIdx.x;
    const int b0  = blockIdx.x * G;
    const float* __restrict__ yb0 = y_in + (size_t)b0 * NS;

    // Stage y: 8 wave-coalesced scalar loads -> 2 conflict-free b128 writes.
    {
        float4 v0, v1;
        v0.x = yb0[0 * NS + tid];       v1.x = yb0[0 * NS + tid + 512];
        v0.y = yb0[1 * NS + tid];       v1.y = yb0[1 * NS + tid + 512];
        v0.z = yb0[2 * NS + tid];       v1.z = yb0[2 * NS + tid + 512];
        v0.w = yb0[3 * NS + tid];       v1.w = yb0[3 * NS + tid + 512];
        y_s[tid]       = v0;
        y_s[tid + 512] = v1;
        if (tid == 0) y_s[NS] = make_float4(1.f, 1.f, 1.f, 1.f);
    }
    __syncthreads();

    const int2 c2 = ((const int2*)cnt_sorted)[tid];  // sorted cols 2t, 2t+1
    const int2 p2 = ((const int2*)perm)[tid];        // their product ids
    const int cmax = max(c2.x, c2.y);                // c0 ~= c1 (sorted-adjacent)

    float4 acc0 = {0.f, 0.f, 0.f, 0.f};
    float4 acc1 = {0.f, 0.f, 0.f, 0.f};

    int4 rec = (cmax > 0) ? ell4[tid] : make_int4(0, 0, 0, 0);
    for (int slot = 0; slot < cmax; ++slot) {
        const int4 nrec = (slot + 1 < cmax) ? ell4[(slot + 1) * (NS / 2) + tid]
                                            : make_int4(0, 0, 0, 0);
        {
            const unsigned ix = (unsigned)rec.x;
            const float4 ya = y_s[ix & 0xFFFFu];
            const float4 yb = y_s[ix >> 16];
            const float  k  = __int_as_float(rec.y);
            acc0.x += k * ya.x * yb.x;
            acc0.y += k * ya.y * yb.y;
            acc0.z += k * ya.z * yb.z;
            acc0.w += k * ya.w * yb.w;
        }
        {
            const unsigned ix = (unsigned)rec.z;
            const float4 ya = y_s[ix & 0xFFFFu];
            const float4 yb = y_s[ix >> 16];
            const float  k  = __int_as_float(rec.w);
            acc1.x += k * ya.x * yb.x;
            acc1.y += k * ya.y * yb.y;
            acc1.z += k * ya.z * yb.z;
            acc1.w += k * ya.w * yb.w;
        }
        rec = nrec;
    }

    a_s[p2.x] = acc0;
    a_s[p2.y] = acc1;
    __syncthreads();

    // Writeback: conflict-free b128 reads, wave-coalesced scalar stores.
    const float t0 = t_in[b0];
    const float t1 = t_in[b0 + 1];
    const float t2 = t_in[b0 + 2];
    const float t3 = t_in[b0 + 3];
    const float4 r0 = a_s[tid];
    const float4 r1 = a_s[tid + 512];
    float* __restrict__ ob0 = y_out + (size_t)b0 * NS;
    ob0[0 * NS + tid] = r0.x * t0;   ob0[0 * NS + tid + 512] = r1.x * t0;
    ob0[1 * NS + tid] = r0.y * t1;   ob0[1 * NS + tid + 512] = r1.y * t1;
    ob0[2 * NS + tid] = r0.z * t2;   ob0[2 * NS + tid + 512] = r1.z * t2;
    ob0[3 * NS + tid] = r0.w * t3;   ob0[3 * NS + tid + 512] = r1.w * t3;
}

extern "C" void kernel_launch(void* const* d_in, const int* in_sizes, int n_in,
                              void* d_out, int out_size, void* d_ws, size_t ws_size,
                              hipStream_t stream) {
    const float* t_in = (const float*)d_in[0];
    const float* y_in = (const float*)d_in[1];
    const float* k1   = (const float*)d_in[2];
    const float* k2   = (const float*)d_in[3];
    const int*   i1r  = (const int*)d_in[4];
    const int*   i1p  = (const int*)d_in[5];
    const int*   i2r  = (const int*)d_in[6];
    const int*   i2p  = (const int*)d_in[7];
    float*       out  = (float*)d_out;

    char* ws = (char*)d_ws;
    int*  counts     = (int*)(ws + WS_COUNTS);
    int*  cursor     = (int*)(ws + WS_CURSOR);
    int2* ell        = (int2*)(ws + WS_ELL);
    int*  perm       = (int*)(ws + WS_PERM);
    int*  iperm      = (int*)(ws + WS_IPERM);
    int*  cnt_sorted = (int*)(ws + WS_CNTS);

    hipMemsetAsync(ws, 0, WS_ZERO_BYTES, stream);   // counts+cursor+ELL
    count_kernel<<<dim3((NRT + 255) / 256), dim3(256), 0, stream>>>(i1p, i2p, counts);
    sort_kernel<<<dim3(1), dim3(1024), 0, stream>>>(counts, perm, iperm, cnt_sorted);
    fill_kernel<<<dim3((NRT + 255) / 256), dim3(256), 0, stream>>>(
        k1, k2, i1r, i1p, i2r, i2p, iperm, cursor, ell);
    reaction_main_kernel<<<dim3(BATCH / G), dim3(MAIN_THREADS), 0, stream>>>(
        t_in, y_in, cnt_sorted, perm, (const int4*)ell, out);
}

// Round 6
// 100.184 us; speedup vs baseline: 1.0609x; 1.0609x over previous
//
#include <hip/hip_runtime.h>

// ReactionTerm — gather formulation, SPLIT-2 ELL-transposed layout.
//
// Key insight from R5: grid exactly fills the device (1024 blocks = 4/CU,
// one round), so kernel time = slowest wave = max product record-count.
// Sorting can't reduce that max; SPLITTING can. Each product's records are
// dealt alternately into 2 half-columns -> per-thread loop bound drops from
// max(c) (~22) to ceil(max(c)/2) (~11) with no rebalancing kernels at all.
//
// ELL: int2[32][2048]; half-col h=2p+(slot&1), row=slot>>1.
//   record = { ia | (ib<<16), bitcast(k) }; 1st-order ib=NS sentinel
//   (y_s[NS]=1.0). Zeroed pad slots decode to k=0 -> contribute 0.
//
// reaction_main_kernel: block = G=4 batch rows x 1024 products, 512 thr.
// Thread t owns products {2t,2t+1} = half-cols {4t..4t+3}: per slot, 2
// lane-consecutive int4 loads (2KB contiguous per wave), 8 ds_read_b128,
// both halves accumulate into the same register acc. No atomics, no second
// barrier; direct coalesced float2 writeback. 4 blocks/CU = 32 waves/CU.

constexpr int BATCH = 4096;
constexpr int NS    = 1024;
constexpr int NR1   = 2048;
constexpr int NR2   = 8192;
constexpr int NRT   = NR1 + NR2;   // 10240
constexpr int G     = 4;
constexpr int MAIN_THREADS = 512;
constexpr int NHALF = 2 * NS;      // 2048 half-columns
constexpr int MAX_HSLOTS = 32;     // per half-col; product count<=64 covered

// d_ws layout (bytes) — no overlaps:
//   cursor : int[1024]            @ 0     (4 KiB)
//   ell    : int2[32*2048]        @ 8192  (512 KiB, ends 532480)
constexpr size_t WS_CURSOR = 0;
constexpr size_t WS_ELL    = 8192;
constexpr size_t WS_ZERO_BYTES = WS_ELL + (size_t)MAX_HSLOTS * NHALF * sizeof(int2);

__global__ __launch_bounds__(256) void fill_kernel(
    const float* __restrict__ k1,  const float* __restrict__ k2,
    const int*   __restrict__ i1r, const int*   __restrict__ i1p,
    const int*   __restrict__ i2r, const int*   __restrict__ i2p,
    int*         __restrict__ cursor,   // [NS], zeroed
    int2*        __restrict__ ell)      // [MAX_HSLOTS][NHALF]
{
    const int i = blockIdx.x * blockDim.x + threadIdx.x;
    if (i < NR1) {
        const int p = i1p[i];
        const int slot = atomicAdd(&cursor[p], 1);
        const int row = slot >> 1;
        if (row < MAX_HSLOTS)
            ell[row * NHALF + 2 * p + (slot & 1)] =
                make_int2(i1r[i] | (NS << 16), __float_as_int(k1[i]));
    } else if (i < NRT) {
        const int r = i - NR1;
        const int p = i2p[r];
        const int slot = atomicAdd(&cursor[p], 1);
        const int row = slot >> 1;
        if (row < MAX_HSLOTS)
            ell[row * NHALF + 2 * p + (slot & 1)] =
                make_int2(i2r[2 * r] | (i2r[2 * r + 1] << 16), __float_as_int(k2[r]));
    }
}

__global__ __launch_bounds__(MAIN_THREADS) void reaction_main_kernel(
    const float* __restrict__ t_in,    // [B]
    const float* __restrict__ y_in,    // [B, NS]
    const int*   __restrict__ counts,  // [NS] final per-product counts
    const int4*  __restrict__ ell4,    // [MAX_HSLOTS][NHALF/2] half-col pairs
    float*       __restrict__ y_out)   // [B, NS]
{
    __shared__ float4 y_s[NS + 1];     // y_s[s] = {y[b0+g][s]}; [NS] = 1.0 sentinel

    const int tid = threadIdx.x;
    const int b0  = blockIdx.x * G;
    const float* __restrict__ yb0 = y_in + (size_t)b0 * NS;

    // Stage y: 8 wave-coalesced scalar loads -> 2 conflict-free b128 writes.
    {
        float4 v0, v1;
        v0.x = yb0[0 * NS + tid];       v1.x = yb0[0 * NS + tid + 512];
        v0.y = yb0[1 * NS + tid];       v1.y = yb0[1 * NS + tid + 512];
        v0.z = yb0[2 * NS + tid];       v1.z = yb0[2 * NS + tid + 512];
        v0.w = yb0[3 * NS + tid];       v1.w = yb0[3 * NS + tid + 512];
        y_s[tid]       = v0;
        y_s[tid + 512] = v1;
        if (tid == 0) y_s[NS] = make_float4(1.f, 1.f, 1.f, 1.f);
    }
    __syncthreads();

    // Products 2t, 2t+1; loop bound = ceil(max(c0,c1)/2) thanks to split-2.
    const int2 c2  = ((const int2*)counts)[tid];
    const int cmax = (max(c2.x, c2.y) + 1) >> 1;

    float4 acc0 = {0.f, 0.f, 0.f, 0.f};   // product 2t   (half-cols 4t,4t+1)
    float4 acc1 = {0.f, 0.f, 0.f, 0.f};   // product 2t+1 (half-cols 4t+2,4t+3)

    const int col4 = 2 * tid;             // int4 index of half-col pair {4t,4t+1}
    constexpr int ROWSTRIDE = NHALF / 2;  // int4s per slot row = 1024

    int4 ra, rb;
    if (cmax > 0) {
        ra = ell4[col4];
        rb = ell4[col4 + 1];
    } else {
        ra = make_int4(0, 0, 0, 0);
        rb = make_int4(0, 0, 0, 0);
    }

    for (int slot = 0; slot < cmax; ++slot) {
        int4 na, nb;
        if (slot + 1 < cmax) {
            na = ell4[(slot + 1) * ROWSTRIDE + col4];
            nb = ell4[(slot + 1) * ROWSTRIDE + col4 + 1];
        } else {
            na = make_int4(0, 0, 0, 0);
            nb = make_int4(0, 0, 0, 0);
        }
        // half-cols 4t (ra.xy) and 4t+1 (ra.zw) -> product 2t
        {
            const unsigned ix = (unsigned)ra.x;
            const float4 ya = y_s[ix & 0xFFFFu];
            const float4 yb = y_s[ix >> 16];
            const float  k  = __int_as_float(ra.y);
            acc0.x += k * ya.x * yb.x;  acc0.y += k * ya.y * yb.y;
            acc0.z += k * ya.z * yb.z;  acc0.w += k * ya.w * yb.w;
        }
        {
            const unsigned ix = (unsigned)ra.z;
            const float4 ya = y_s[ix & 0xFFFFu];
            const float4 yb = y_s[ix >> 16];
            const float  k  = __int_as_float(ra.w);
            acc0.x += k * ya.x * yb.x;  acc0.y += k * ya.y * yb.y;
            acc0.z += k * ya.z * yb.z;  acc0.w += k * ya.w * yb.w;
        }
        // half-cols 4t+2 (rb.xy) and 4t+3 (rb.zw) -> product 2t+1
        {
            const unsigned ix = (unsigned)rb.x;
            const float4 ya = y_s[ix & 0xFFFFu];
            const float4 yb = y_s[ix >> 16];
            const float  k  = __int_as_float(rb.y);
            acc1.x += k * ya.x * yb.x;  acc1.y += k * ya.y * yb.y;
            acc1.z += k * ya.z * yb.z;  acc1.w += k * ya.w * yb.w;
        }
        {
            const unsigned ix = (unsigned)rb.z;
            const float4 ya = y_s[ix & 0xFFFFu];
            const float4 yb = y_s[ix >> 16];
            const float  k  = __int_as_float(rb.w);
            acc1.x += k * ya.x * yb.x;  acc1.y += k * ya.y * yb.y;
            acc1.z += k * ya.z * yb.z;  acc1.w += k * ya.w * yb.w;
        }
        ra = na;
        rb = nb;
    }

    const float t0 = t_in[b0];
    const float t1 = t_in[b0 + 1];
    const float t2 = t_in[b0 + 2];
    const float t3 = t_in[b0 + 3];

    const int p0 = tid * 2;
    float* __restrict__ ob0 = y_out + (size_t)b0 * NS;
    *(float2*)(ob0 + 0 * NS + p0) = make_float2(acc0.x * t0, acc1.x * t0);
    *(float2*)(ob0 + 1 * NS + p0) = make_float2(acc0.y * t1, acc1.y * t1);
    *(float2*)(ob0 + 2 * NS + p0) = make_float2(acc0.z * t2, acc1.z * t2);
    *(float2*)(ob0 + 3 * NS + p0) = make_float2(acc0.w * t3, acc1.w * t3);
}

extern "C" void kernel_launch(void* const* d_in, const int* in_sizes, int n_in,
                              void* d_out, int out_size, void* d_ws, size_t ws_size,
                              hipStream_t stream) {
    const float* t_in = (const float*)d_in[0];
    const float* y_in = (const float*)d_in[1];
    const float* k1   = (const float*)d_in[2];
    const float* k2   = (const float*)d_in[3];
    const int*   i1r  = (const int*)d_in[4];
    const int*   i1p  = (const int*)d_in[5];
    const int*   i2r  = (const int*)d_in[6];
    const int*   i2p  = (const int*)d_in[7];
    float*       out  = (float*)d_out;

    char* ws = (char*)d_ws;
    int*  cursor = (int*)(ws + WS_CURSOR);
    int2* ell    = (int2*)(ws + WS_ELL);

    hipMemsetAsync(ws, 0, WS_ZERO_BYTES, stream);   // cursor + ELL
    fill_kernel<<<dim3((NRT + 255) / 256), dim3(256), 0, stream>>>(
        k1, k2, i1r, i1p, i2r, i2p, cursor, ell);
    reaction_main_kernel<<<dim3(BATCH / G), dim3(MAIN_THREADS), 0, stream>>>(
        t_in, y_in, cursor, (const int4*)ell, out);
}